// Round 1
// baseline (13820.882 us; speedup 1.0000x reference)
//
#include <hip/hip_runtime.h>
#include <math.h>
#include <stdint.h>

// Problem constants
constexpr int LL = 4096;   // seq len
constexpr int EE = 300;    // embedding dim
constexpr int HH = 256;    // per-direction hidden (H2)
constexpr int NGATE = 1024;// 4*HH
constexpr int TT = 16;     // tagset
constexpr float NEGV = -10000.0f;

// Workspace layout (byte offsets, 256B-aligned)
constexpr size_t OFF_CNT  = 0;                              // int counters (2 dirs, separate lines)
constexpr size_t OFF_X    = 512;                            // L*E f32      = 4,915,200 B
constexpr size_t OFF_ZX   = OFF_X    + (size_t)LL*EE*4;     // 2*L*1024 f32 = 33,554,432 B
constexpr size_t OFF_HALL = OFF_ZX   + (size_t)2*LL*NGATE*4;// 2*L*256 f32  = 8,388,608 B
constexpr size_t OFF_HBUF = OFF_HALL + (size_t)2*LL*HH*4;   // 2*2*256 f32  = 4,096 B
constexpr size_t OFF_FE   = OFF_HBUF + 4096;                // L*16 f32     = 262,144 B

// ---------------------------------------------------------------------------
// Kernel 1: embedding gather  X[t][e] = emb[sentence[t]][e]
// ---------------------------------------------------------------------------
__global__ void gather_x(const int* __restrict__ sent, const float* __restrict__ emb,
                         float* __restrict__ X) {
  const int i = blockIdx.x * blockDim.x + threadIdx.x;   // over L * (E/4) float4s
  const int total = LL * (EE / 4);
  if (i >= total) return;
  const int row = i / (EE / 4), c4 = i % (EE / 4);
  const int v = sent[row];
  reinterpret_cast<float4*>(X)[(size_t)row * (EE / 4) + c4] =
      reinterpret_cast<const float4*>(emb + (size_t)v * EE)[c4];
}

// ---------------------------------------------------------------------------
// Kernel 2: input GEMM  Zx[dir][t][n] = X[t]·W_ih[n] + b[n]
// 64x64 tile, 256 threads, 4x4 micro-tile, K staged in LDS (transposed)
// ---------------------------------------------------------------------------
__global__ __launch_bounds__(256) void input_gemm(
    const float* __restrict__ X, const float* __restrict__ w_f,
    const float* __restrict__ b_f, const float* __restrict__ w_b,
    const float* __restrict__ b_b, float* __restrict__ ZX) {
  const int dir = blockIdx.z;
  const float* __restrict__ W  = dir ? w_b : w_f;
  const float* __restrict__ Bv = dir ? b_b : b_f;
  float* __restrict__ Z = ZX + (size_t)dir * LL * NGATE;
  __shared__ float As[32][68];   // [k][m], stride 68 (272B, 16B aligned)
  __shared__ float Bs[32][68];   // [k][n]
  const int m0 = blockIdx.y * 64, n0 = blockIdx.x * 64;
  const int t = threadIdx.x;
  const int tx = t & 15, ty = t >> 4;
  float acc[4][4] = {};
  for (int k0 = 0; k0 < EE; k0 += 32) {
#pragma unroll
    for (int r = 0; r < 2; ++r) {
      const int idx = t + r * 256;       // 0..511
      const int row = idx >> 3;          // 0..63
      const int kk4 = (idx & 7) << 2;    // 0,4,..,28
      const int k = k0 + kk4;
      float4 va = make_float4(0.f, 0.f, 0.f, 0.f), vb = va;
      if (k < EE) {
        va = *reinterpret_cast<const float4*>(X + (size_t)(m0 + row) * EE + k);
        vb = *reinterpret_cast<const float4*>(W + (size_t)(n0 + row) * EE + k);
      }
      As[kk4 + 0][row] = va.x; As[kk4 + 1][row] = va.y;
      As[kk4 + 2][row] = va.z; As[kk4 + 3][row] = va.w;
      Bs[kk4 + 0][row] = vb.x; Bs[kk4 + 1][row] = vb.y;
      Bs[kk4 + 2][row] = vb.z; Bs[kk4 + 3][row] = vb.w;
    }
    __syncthreads();
    const int kmax = (EE - k0 < 32) ? (EE - k0) : 32;
    for (int k = 0; k < kmax; ++k) {
      const float4 av = *reinterpret_cast<const float4*>(&As[k][ty << 2]);
      const float4 bv = *reinterpret_cast<const float4*>(&Bs[k][tx << 2]);
      acc[0][0] += av.x * bv.x; acc[0][1] += av.x * bv.y; acc[0][2] += av.x * bv.z; acc[0][3] += av.x * bv.w;
      acc[1][0] += av.y * bv.x; acc[1][1] += av.y * bv.y; acc[1][2] += av.y * bv.z; acc[1][3] += av.y * bv.w;
      acc[2][0] += av.z * bv.x; acc[2][1] += av.z * bv.y; acc[2][2] += av.z * bv.z; acc[2][3] += av.z * bv.w;
      acc[3][0] += av.w * bv.x; acc[3][1] += av.w * bv.y; acc[3][2] += av.w * bv.z; acc[3][3] += av.w * bv.w;
    }
    __syncthreads();
  }
#pragma unroll
  for (int i = 0; i < 4; ++i)
#pragma unroll
    for (int j = 0; j < 4; ++j) {
      const int m = m0 + (ty << 2) + i, n = n0 + (tx << 2) + j;
      Z[(size_t)m * NGATE + n] = acc[i][j] + Bv[n];
    }
}

// ---------------------------------------------------------------------------
// Kernel 3: persistent bidirectional LSTM recurrence.
// 8 blocks x 512 threads: dir = blockIdx&1, g = blockIdx>>1 (4 WGs per dir).
// WG g owns hidden units [g*64, g*64+64) -> 256 gate rows, all 256 k.
// Weights live entirely in VGPRs: thread (rq=t&63, kq=t>>6) holds
// w[4 rows][32 k] for local rows 4rq..4rq+3, k in [kq*32, kq*32+32).
// Per step: 128 reg-FMAs -> LDS partial reduce -> 64 gate lanes -> h slice to
// global double-buffer -> release atomic; spin-acquire on a per-dir counter.
// ---------------------------------------------------------------------------
__global__ __launch_bounds__(512, 2) void recurrence(
    const float* __restrict__ whh_f, const float* __restrict__ whh_b,
    const float* __restrict__ h0, const float* __restrict__ c0,
    const float* __restrict__ ZX, float* __restrict__ HALL,
    float* __restrict__ HBUF, int* __restrict__ CNT) {
  const int t = threadIdx.x;
  const int dir = blockIdx.x & 1;
  const int g = blockIdx.x >> 1;
  const float* __restrict__ Whh = dir ? whh_b : whh_f;
  const float* __restrict__ Z = ZX + (size_t)dir * LL * NGATE;
  float* __restrict__ Hbuf = HBUF + dir * 2 * HH;          // [parity][HH]
  float* __restrict__ Hall = HALL + (size_t)dir * LL * HH;
  int* cnt = CNT + dir * 64;                               // separate cachelines
  const int rq = t & 63;
  const int kq = t >> 6;
  const int kbase = kq << 5;

  // Load weight registers (one-time)
  float w[4][32];
#pragma unroll
  for (int j = 0; j < 4; ++j) {
    const int lr = (rq << 2) + j;                 // local row 0..255
    const int grow = ((lr >> 6) << 8) + (g << 6) + (lr & 63); // q*256 + g*64 + u
    const float* wr = Whh + (size_t)grow * HH + kbase;
#pragma unroll
    for (int kk = 0; kk < 32; kk += 4) {
      const float4 v = *reinterpret_cast<const float4*>(wr + kk);
      w[j][kk] = v.x; w[j][kk + 1] = v.y; w[j][kk + 2] = v.z; w[j][kk + 3] = v.w;
    }
  }

  __shared__ float part[8][260];   // [kq][local row], padded

  float c_reg = 0.f;
  if (t < 64) {
    c_reg = c0[dir * HH + (g << 6) + t];
    Hbuf[HH + (g << 6) + t] = h0[dir * HH + (g << 6) + t];  // parity 1 = h_{-1}
  }
  if (t == 0)
    __hip_atomic_fetch_add(cnt, 1, __ATOMIC_RELEASE, __HIP_MEMORY_SCOPE_AGENT);

  // prefetch Zx for step 0
  float zx0 = 0.f, zx1 = 0.f, zx2 = 0.f, zx3 = 0.f;
  if (t < 64) {
    const int trow0 = dir ? (LL - 1) : 0;
    const float* zp = Z + (size_t)trow0 * NGATE + (g << 6) + t;
    zx0 = zp[0]; zx1 = zp[HH]; zx2 = zp[2 * HH]; zx3 = zp[3 * HH];
  }

  for (int s = 0; s < LL; ++s) {
    // prefetch next step's Zx (hides HBM latency behind spin+compute)
    float nzx0 = 0.f, nzx1 = 0.f, nzx2 = 0.f, nzx3 = 0.f;
    if (t < 64 && s + 1 < LL) {
      const int trow = dir ? (LL - 2 - s) : (s + 1);
      const float* zp = Z + (size_t)trow * NGATE + (g << 6) + t;
      nzx0 = zp[0]; nzx1 = zp[HH]; nzx2 = zp[2 * HH]; nzx3 = zp[3 * HH];
    }
    if (t == 0) {
      const int target = 4 * (s + 1);
      while (__hip_atomic_load(cnt, __ATOMIC_ACQUIRE, __HIP_MEMORY_SCOPE_AGENT) < target) {}
    }
    __syncthreads();
    __builtin_amdgcn_fence(__ATOMIC_ACQUIRE, "agent");

    // read h_{s-1} slice (double-buffered by parity)
    const float* hp = Hbuf + (((s & 1) ^ 1) << 8) + kbase;
    float hv[32];
#pragma unroll
    for (int kk = 0; kk < 32; kk += 4) {
      const float4 v = *reinterpret_cast<const float4*>(hp + kk);
      hv[kk] = v.x; hv[kk + 1] = v.y; hv[kk + 2] = v.z; hv[kk + 3] = v.w;
    }
    float a0 = 0.f, a1 = 0.f, a2 = 0.f, a3 = 0.f;
#pragma unroll
    for (int kk = 0; kk < 32; ++kk) {
      const float h = hv[kk];
      a0 += w[0][kk] * h; a1 += w[1][kk] * h; a2 += w[2][kk] * h; a3 += w[3][kk] * h;
    }
    *reinterpret_cast<float4*>(&part[kq][rq << 2]) = make_float4(a0, a1, a2, a3);
    __syncthreads();

    if (t < 64) {
      float z0 = zx0, z1 = zx1, z2 = zx2, z3 = zx3;
#pragma unroll
      for (int k2 = 0; k2 < 8; ++k2) {
        z0 += part[k2][t];
        z1 += part[k2][64 + t];
        z2 += part[k2][128 + t];
        z3 += part[k2][192 + t];
      }
      const float ig = 1.f / (1.f + expf(-z0));
      const float fg = 1.f / (1.f + expf(-z1));
      const float gg = tanhf(z2);
      const float og = 1.f / (1.f + expf(-z3));
      c_reg = fg * c_reg + ig * gg;
      const float hval = og * tanhf(c_reg);
      const int trow = dir ? (LL - 1 - s) : s;
      Hbuf[((s & 1) << 8) + (g << 6) + t] = hval;
      Hall[(size_t)trow * HH + (g << 6) + t] = hval;
    }
    if (t == 0)
      __hip_atomic_fetch_add(cnt, 1, __ATOMIC_RELEASE, __HIP_MEMORY_SCOPE_AGENT);
    zx0 = nzx0; zx1 = nzx1; zx2 = nzx2; zx3 = nzx3;
  }
}

// ---------------------------------------------------------------------------
// Kernel 4: feats[t][j] = b_out[j] + Hf[t]·Wout[j][0:256] + Hb[t]·Wout[j][256:512]
// ---------------------------------------------------------------------------
__global__ __launch_bounds__(256) void feats_gemm(
    const float* __restrict__ HALL, const float* __restrict__ Wout,
    const float* __restrict__ bout, float* __restrict__ FE) {
  __shared__ float Wl[16][516];   // padded against bank conflicts
  const int t = threadIdx.x;
  for (int i = t; i < 16 * 512; i += 256) Wl[i >> 9][i & 511] = Wout[i];
  __syncthreads();
  const int row = blockIdx.x * 16 + (t >> 4);
  const int j = t & 15;
  const float* hf = HALL + (size_t)row * HH;
  const float* hb = HALL + (size_t)LL * HH + (size_t)row * HH;
  float acc = bout[j];
  for (int k = 0; k < HH; k += 4) {
    const float4 a = *reinterpret_cast<const float4*>(hf + k);
    const float4 wa = *reinterpret_cast<const float4*>(&Wl[j][k]);
    acc += a.x * wa.x + a.y * wa.y + a.z * wa.z + a.w * wa.w;
    const float4 b2 = *reinterpret_cast<const float4*>(hb + k);
    const float4 wb = *reinterpret_cast<const float4*>(&Wl[j][256 + k]);
    acc += b2.x * wb.x + b2.y * wb.y + b2.z * wb.z + b2.w * wb.w;
  }
  FE[(size_t)row * TT + j] = acc;
}

// ---------------------------------------------------------------------------
// Kernel 5: Viterbi. Forward on wave 0 (lane = n*4 + pg, pg covers 4 prevs):
// local argmax over 4, quad_perm DPP reduce over pg, ds_bpermute redistribute.
// Backpointers in LDS (u8 [4096][16]); chunk-parallel backtrack.
// ---------------------------------------------------------------------------
template <int CTRL>
__device__ __forceinline__ int dpp_i(int v) {
  return __builtin_amdgcn_mov_dpp(v, CTRL, 0xF, 0xF, true);
}
template <int CTRL>
__device__ __forceinline__ float dpp_f(float v) {
  return __int_as_float(__builtin_amdgcn_mov_dpp(__float_as_int(v), CTRL, 0xF, 0xF, true));
}
__device__ __forceinline__ float bperm_f(int lane, float v) {
  return __int_as_float(__builtin_amdgcn_ds_bpermute(lane << 2, __float_as_int(v)));
}

__global__ __launch_bounds__(1024) void viterbi(
    const float* __restrict__ FE, const float* __restrict__ trans,
    float* __restrict__ out) {
  __shared__ unsigned char bp8[LL * TT];   // 64 KB backpointers
  __shared__ unsigned char xc[64 * 16];    // chunk exit tables
  __shared__ unsigned char entry[64];      // chunk entry tags
  __shared__ int sbest;
  const int t = threadIdx.x;

  if (t < 64) {
    const int n = t >> 2, pg = t & 3;
    const float tr0 = trans[n * 16 + (pg << 2) + 0];
    const float tr1 = trans[n * 16 + (pg << 2) + 1];
    const float tr2 = trans[n * 16 + (pg << 2) + 2];
    const float tr3 = trans[n * 16 + (pg << 2) + 3];
    float fvp0 = ((pg << 2) + 0 == 14) ? 0.f : NEGV;
    float fvp1 = ((pg << 2) + 1 == 14) ? 0.f : NEGV;
    float fvp2 = ((pg << 2) + 2 == 14) ? 0.f : NEGV;
    float fvp3 = ((pg << 2) + 3 == 14) ? 0.f : NEGV;

    auto step = [&](int s, float feat) {
      float bv = fvp0 + tr0; int bi = (pg << 2);
      float c;
      c = fvp1 + tr1; if (c > bv) { bv = c; bi = (pg << 2) + 1; }
      c = fvp2 + tr2; if (c > bv) { bv = c; bi = (pg << 2) + 2; }
      c = fvp3 + tr3; if (c > bv) { bv = c; bi = (pg << 2) + 3; }
      float pv = dpp_f<0xB1>(bv); int pi = dpp_i<0xB1>(bi);   // xor 1 in quad
      if (pv > bv || (pv == bv && pi < bi)) { bv = pv; bi = pi; }
      pv = dpp_f<0x4E>(bv); pi = dpp_i<0x4E>(bi);             // xor 2 in quad
      if (pv > bv || (pv == bv && pi < bi)) { bv = pv; bi = pi; }
      if (pg == 0) bp8[(s << 4) + n] = (unsigned char)bi;
      const float fvn = bv + feat;
      fvp0 = bperm_f((pg << 4) + 0,  fvn);
      fvp1 = bperm_f((pg << 4) + 4,  fvn);
      fvp2 = bperm_f((pg << 4) + 8,  fvn);
      fvp3 = bperm_f((pg << 4) + 12, fvn);
    };

    // 4-deep feat prefetch to cover L2/L3 latency
    float fb0 = FE[(0 << 4) + n], fb1 = FE[(1 << 4) + n];
    float fb2 = FE[(2 << 4) + n], fb3 = FE[(3 << 4) + n];
    for (int s = 0; s < LL; s += 4) {
      step(s + 0, fb0); fb0 = (s + 4 < LL) ? FE[((s + 4) << 4) + n] : 0.f;
      step(s + 1, fb1); fb1 = (s + 5 < LL) ? FE[((s + 5) << 4) + n] : 0.f;
      step(s + 2, fb2); fb2 = (s + 6 < LL) ? FE[((s + 6) << 4) + n] : 0.f;
      step(s + 3, fb3); fb3 = (s + 7 < LL) ? FE[((s + 7) << 4) + n] : 0.f;
    }

    // terminal: fv + transitions[STOP=15][p]
    const float tt0 = trans[240 + (pg << 2) + 0];
    const float tt1 = trans[240 + (pg << 2) + 1];
    const float tt2 = trans[240 + (pg << 2) + 2];
    const float tt3 = trans[240 + (pg << 2) + 3];
    float bv = fvp0 + tt0; int bi = (pg << 2);
    float c;
    c = fvp1 + tt1; if (c > bv) { bv = c; bi = (pg << 2) + 1; }
    c = fvp2 + tt2; if (c > bv) { bv = c; bi = (pg << 2) + 2; }
    c = fvp3 + tt3; if (c > bv) { bv = c; bi = (pg << 2) + 3; }
    float pv = dpp_f<0xB1>(bv); int pi = dpp_i<0xB1>(bi);
    if (pv > bv || (pv == bv && pi < bi)) { bv = pv; bi = pi; }
    pv = dpp_f<0x4E>(bv); pi = dpp_i<0x4E>(bi);
    if (pv > bv || (pv == bv && pi < bi)) { bv = pv; bi = pi; }
    if (t == 0) { out[0] = bv; sbest = bi; }
  }
  __syncthreads();

  // Phase 1: per-chunk exit tables (1024 threads = 64 chunks x 16 entry tags)
  {
    const int c = t >> 4, e = t & 15;
    int tag = e;
#pragma unroll 1
    for (int i = 63; i >= 0; --i) tag = bp8[(((c << 6) + i) << 4) + tag];
    xc[(c << 4) + e] = (unsigned char)tag;
  }
  __syncthreads();
  // Phase 2: sequential chunk composition
  if (t == 0) {
    int carry = sbest;
#pragma unroll 1
    for (int c = 63; c >= 0; --c) {
      entry[c] = (unsigned char)carry;
      carry = xc[(c << 4) + carry];
    }
  }
  __syncthreads();
  // Phase 3: emit path, chunks in parallel
  if (t < 64) {
    const int c = t;
    int tag = entry[c];
#pragma unroll 1
    for (int i = 63; i >= 0; --i) {
      const int s = (c << 6) + i;
      out[1 + s] = (float)tag;
      tag = bp8[(s << 4) + tag];
    }
  }
}

// ---------------------------------------------------------------------------
extern "C" void kernel_launch(void* const* d_in, const int* in_sizes, int n_in,
                              void* d_out, int out_size, void* d_ws, size_t ws_size,
                              hipStream_t stream) {
  const int*   sent = (const int*)d_in[0];
  const float* emb  = (const float*)d_in[1];
  const float* wihf = (const float*)d_in[2];
  const float* whhf = (const float*)d_in[3];
  const float* bf   = (const float*)d_in[4];
  const float* wihb = (const float*)d_in[5];
  const float* whhb = (const float*)d_in[6];
  const float* bb   = (const float*)d_in[7];
  const float* wout = (const float*)d_in[8];
  const float* bout = (const float*)d_in[9];
  const float* trans= (const float*)d_in[10];
  const float* h0   = (const float*)d_in[11];
  const float* c0   = (const float*)d_in[12];
  float* out = (float*)d_out;
  char* ws = (char*)d_ws;

  int*   CNT  = (int*)(ws + OFF_CNT);
  float* X    = (float*)(ws + OFF_X);
  float* ZX   = (float*)(ws + OFF_ZX);
  float* HALL = (float*)(ws + OFF_HALL);
  float* HBUF = (float*)(ws + OFF_HBUF);
  float* FE   = (float*)(ws + OFF_FE);

  hipMemsetAsync(CNT, 0, 512, stream);
  gather_x<<<(LL * (EE / 4) + 255) / 256, 256, 0, stream>>>(sent, emb, X);
  input_gemm<<<dim3(16, 64, 2), 256, 0, stream>>>(X, wihf, bf, wihb, bb, ZX);
  recurrence<<<8, 512, 0, stream>>>(whhf, whhb, h0, c0, ZX, HALL, HBUF, CNT);
  feats_gemm<<<LL / 16, 256, 0, stream>>>(HALL, wout, bout, FE);
  viterbi<<<1, 1024, 0, stream>>>(FE, trans, out);
}

// Round 2
// 8288.119 us; speedup vs baseline: 1.6676x; 1.6676x over previous
//
#include <hip/hip_runtime.h>
#include <math.h>
#include <stdint.h>

// Problem constants
constexpr int LL = 4096;   // seq len
constexpr int EE = 300;    // embedding dim
constexpr int HH = 256;    // per-direction hidden (H2)
constexpr int NGATE = 1024;// 4*HH
constexpr int TT = 16;     // tagset
constexpr float NEGV = -10000.0f;

// Workspace layout (byte offsets)
// SLOT: tagged h exchange, [dir][parity][256] x u64 = 8192 B
constexpr size_t OFF_SLOT = 0;
constexpr size_t OFF_X    = 8192;                           // L*E f32
constexpr size_t OFF_ZX   = OFF_X    + (size_t)LL*EE*4;     // 2*L*1024 f32
constexpr size_t OFF_HALL = OFF_ZX   + (size_t)2*LL*NGATE*4;// 2*L*256 f32
constexpr size_t OFF_FE   = OFF_HALL + (size_t)2*LL*HH*4;   // L*16 f32

// ---------------------------------------------------------------------------
// Kernel 1: embedding gather  X[t][e] = emb[sentence[t]][e]
// ---------------------------------------------------------------------------
__global__ void gather_x(const int* __restrict__ sent, const float* __restrict__ emb,
                         float* __restrict__ X) {
  const int i = blockIdx.x * blockDim.x + threadIdx.x;   // over L * (E/4) float4s
  const int total = LL * (EE / 4);
  if (i >= total) return;
  const int row = i / (EE / 4), c4 = i % (EE / 4);
  const int v = sent[row];
  reinterpret_cast<float4*>(X)[(size_t)row * (EE / 4) + c4] =
      reinterpret_cast<const float4*>(emb + (size_t)v * EE)[c4];
}

// ---------------------------------------------------------------------------
// Kernel 2: input GEMM  Zx[dir][t][n] = X[t]·W_ih[n] + b[n]
// ---------------------------------------------------------------------------
__global__ __launch_bounds__(256) void input_gemm(
    const float* __restrict__ X, const float* __restrict__ w_f,
    const float* __restrict__ b_f, const float* __restrict__ w_b,
    const float* __restrict__ b_b, float* __restrict__ ZX) {
  const int dir = blockIdx.z;
  const float* __restrict__ W  = dir ? w_b : w_f;
  const float* __restrict__ Bv = dir ? b_b : b_f;
  float* __restrict__ Z = ZX + (size_t)dir * LL * NGATE;
  __shared__ float As[32][68];
  __shared__ float Bs[32][68];
  const int m0 = blockIdx.y * 64, n0 = blockIdx.x * 64;
  const int t = threadIdx.x;
  const int tx = t & 15, ty = t >> 4;
  float acc[4][4] = {};
  for (int k0 = 0; k0 < EE; k0 += 32) {
#pragma unroll
    for (int r = 0; r < 2; ++r) {
      const int idx = t + r * 256;
      const int row = idx >> 3;
      const int kk4 = (idx & 7) << 2;
      const int k = k0 + kk4;
      float4 va = make_float4(0.f, 0.f, 0.f, 0.f), vb = va;
      if (k < EE) {
        va = *reinterpret_cast<const float4*>(X + (size_t)(m0 + row) * EE + k);
        vb = *reinterpret_cast<const float4*>(W + (size_t)(n0 + row) * EE + k);
      }
      As[kk4 + 0][row] = va.x; As[kk4 + 1][row] = va.y;
      As[kk4 + 2][row] = va.z; As[kk4 + 3][row] = va.w;
      Bs[kk4 + 0][row] = vb.x; Bs[kk4 + 1][row] = vb.y;
      Bs[kk4 + 2][row] = vb.z; Bs[kk4 + 3][row] = vb.w;
    }
    __syncthreads();
    const int kmax = (EE - k0 < 32) ? (EE - k0) : 32;
    for (int k = 0; k < kmax; ++k) {
      const float4 av = *reinterpret_cast<const float4*>(&As[k][ty << 2]);
      const float4 bv = *reinterpret_cast<const float4*>(&Bs[k][tx << 2]);
      acc[0][0] += av.x * bv.x; acc[0][1] += av.x * bv.y; acc[0][2] += av.x * bv.z; acc[0][3] += av.x * bv.w;
      acc[1][0] += av.y * bv.x; acc[1][1] += av.y * bv.y; acc[1][2] += av.y * bv.z; acc[1][3] += av.y * bv.w;
      acc[2][0] += av.z * bv.x; acc[2][1] += av.z * bv.y; acc[2][2] += av.z * bv.z; acc[2][3] += av.z * bv.w;
      acc[3][0] += av.w * bv.x; acc[3][1] += av.w * bv.y; acc[3][2] += av.w * bv.z; acc[3][3] += av.w * bv.w;
    }
    __syncthreads();
  }
#pragma unroll
  for (int i = 0; i < 4; ++i)
#pragma unroll
    for (int j = 0; j < 4; ++j) {
      const int m = m0 + (ty << 2) + i, n = n0 + (tx << 2) + j;
      Z[(size_t)m * NGATE + n] = acc[i][j] + Bv[n];
    }
}

// ---------------------------------------------------------------------------
// Kernel 3: persistent bidirectional LSTM recurrence.
// 8 blocks x 512 threads: dir = blockIdx&1, g = blockIdx>>1 (4 WGs per dir).
// h exchange: tagged 64-bit RELAXED agent atomics (tag=step in hi32, f32 bits
// in lo32), double-buffered by step parity. No acquire/release -> no
// buffer_inv/wbl2 cache maintenance on the critical path. Foreign h polled
// into LDS; matvec reads h from LDS.
// Safety: slot(par) written at tag T is only overwritten (tag T+2) after the
// writer passed its poll of tag T+1, which requires every peer WG published
// T+1, which requires they already consumed tag T.
// ---------------------------------------------------------------------------
__global__ __launch_bounds__(512, 2) void recurrence(
    const float* __restrict__ whh_f, const float* __restrict__ whh_b,
    const float* __restrict__ h0, const float* __restrict__ c0,
    const float* __restrict__ ZX, float* __restrict__ HALL,
    unsigned long long* __restrict__ SLOT) {
  const int t = threadIdx.x;
  const int dir = blockIdx.x & 1;
  const int g = blockIdx.x >> 1;
  const float* __restrict__ Whh = dir ? whh_b : whh_f;
  const float* __restrict__ Z = ZX + (size_t)dir * LL * NGATE;
  float* __restrict__ Hall = HALL + (size_t)dir * LL * HH;
  unsigned long long* __restrict__ slotD = SLOT + dir * 2 * HH; // [par][256]
  const int rq = t & 63;
  const int kq = t >> 6;
  const int kbase = kq << 5;

  // Load weight registers (one-time): thread (rq,kq) holds rows 4rq..4rq+3
  // (local to this WG's 64 units x 4 gates), k in [kq*32, kq*32+32)
  float w[4][32];
#pragma unroll
  for (int j = 0; j < 4; ++j) {
    const int lr = (rq << 2) + j;
    const int grow = ((lr >> 6) << 8) + (g << 6) + (lr & 63); // gate*256 + g*64 + u
    const float* wr = Whh + (size_t)grow * HH + kbase;
#pragma unroll
    for (int kk = 0; kk < 32; kk += 4) {
      const float4 v = *reinterpret_cast<const float4*>(wr + kk);
      w[j][kk] = v.x; w[j][kk + 1] = v.y; w[j][kk + 2] = v.z; w[j][kk + 3] = v.w;
    }
  }

  __shared__ float part[8][260];   // [kq][local gate row]
  __shared__ float hsh[2][256];    // [parity][h], full hidden vector

  float c_reg = 0.f;
  if (t < 64) {
    const int u = (g << 6) + t;
    c_reg = c0[dir * HH + u];
    const float h0v = h0[dir * HH + u];
    hsh[0][u] = h0v;
    const unsigned long long v0 = ((unsigned long long)0u << 32) | (unsigned long long)__float_as_uint(h0v);
    __hip_atomic_store(&slotD[u], v0, __ATOMIC_RELAXED, __HIP_MEMORY_SCOPE_AGENT);
  }

  // prefetch Zx for step 0
  float zx0 = 0.f, zx1 = 0.f, zx2 = 0.f, zx3 = 0.f;
  if (t < 64) {
    const int trow0 = dir ? (LL - 1) : 0;
    const float* zp = Z + (size_t)trow0 * NGATE + (g << 6) + t;
    zx0 = zp[0]; zx1 = zp[HH]; zx2 = zp[2 * HH]; zx3 = zp[3 * HH];
  }

  for (int s = 0; s < LL; ++s) {
    const int par = s & 1;
    // prefetch next step's Zx
    float nzx0 = 0.f, nzx1 = 0.f, nzx2 = 0.f, nzx3 = 0.f;
    if (t < 64 && s + 1 < LL) {
      const int trow = dir ? (LL - 2 - s) : (s + 1);
      const float* zp = Z + (size_t)trow * NGATE + (g << 6) + t;
      nzx0 = zp[0]; nzx1 = zp[HH]; nzx2 = zp[2 * HH]; nzx3 = zp[3 * HH];
    }
    // poll foreign h slots (tag == s), fill LDS
    if (t < 256 && (t >> 6) != g) {
      const unsigned long long* sp = &slotD[par * HH + t];
      unsigned long long v;
      do {
        v = __hip_atomic_load(sp, __ATOMIC_RELAXED, __HIP_MEMORY_SCOPE_AGENT);
      } while ((unsigned)(v >> 32) != (unsigned)s);
      hsh[par][t] = __uint_as_float((unsigned)v);
    }
    __syncthreads();

    // matvec: h slice from LDS (broadcast within each 64-lane k-group)
    const float* hp = &hsh[par][kbase];
    float hv[32];
#pragma unroll
    for (int kk = 0; kk < 32; kk += 4) {
      const float4 v = *reinterpret_cast<const float4*>(hp + kk);
      hv[kk] = v.x; hv[kk + 1] = v.y; hv[kk + 2] = v.z; hv[kk + 3] = v.w;
    }
    float a0 = 0.f, a1 = 0.f, a2 = 0.f, a3 = 0.f;
#pragma unroll
    for (int kk = 0; kk < 32; ++kk) {
      const float h = hv[kk];
      a0 += w[0][kk] * h; a1 += w[1][kk] * h; a2 += w[2][kk] * h; a3 += w[3][kk] * h;
    }
    *reinterpret_cast<float4*>(&part[kq][rq << 2]) = make_float4(a0, a1, a2, a3);
    __syncthreads();

    if (t < 64) {
      float z0 = zx0, z1 = zx1, z2 = zx2, z3 = zx3;
#pragma unroll
      for (int k2 = 0; k2 < 8; ++k2) {
        z0 += part[k2][t];
        z1 += part[k2][64 + t];
        z2 += part[k2][128 + t];
        z3 += part[k2][192 + t];
      }
      const float ig = 1.f / (1.f + expf(-z0));
      const float fg = 1.f / (1.f + expf(-z1));
      const float gg = tanhf(z2);
      const float og = 1.f / (1.f + expf(-z3));
      c_reg = fg * c_reg + ig * gg;
      const float hval = og * tanhf(c_reg);
      const int u = (g << 6) + t;
      // publish ASAP: tagged atomic store (tag = s+1), parity (s+1)&1
      const unsigned long long v =
          ((unsigned long long)(unsigned)(s + 1) << 32) | (unsigned long long)__float_as_uint(hval);
      __hip_atomic_store(&slotD[((s + 1) & 1) * HH + u], v, __ATOMIC_RELAXED, __HIP_MEMORY_SCOPE_AGENT);
      hsh[(s + 1) & 1][u] = hval;
      const int trow = dir ? (LL - 1 - s) : s;
      Hall[(size_t)trow * HH + u] = hval;
    }
    zx0 = nzx0; zx1 = nzx1; zx2 = nzx2; zx3 = nzx3;
  }
}

// ---------------------------------------------------------------------------
// Kernel 4: feats[t][j] = b_out[j] + Hf[t]·Wout[j][0:256] + Hb[t]·Wout[j][256:512]
// ---------------------------------------------------------------------------
__global__ __launch_bounds__(256) void feats_gemm(
    const float* __restrict__ HALL, const float* __restrict__ Wout,
    const float* __restrict__ bout, float* __restrict__ FE) {
  __shared__ float Wl[16][516];
  const int t = threadIdx.x;
  for (int i = t; i < 16 * 512; i += 256) Wl[i >> 9][i & 511] = Wout[i];
  __syncthreads();
  const int row = blockIdx.x * 16 + (t >> 4);
  const int j = t & 15;
  const float* hf = HALL + (size_t)row * HH;
  const float* hb = HALL + (size_t)LL * HH + (size_t)row * HH;
  float acc = bout[j];
  for (int k = 0; k < HH; k += 4) {
    const float4 a = *reinterpret_cast<const float4*>(hf + k);
    const float4 wa = *reinterpret_cast<const float4*>(&Wl[j][k]);
    acc += a.x * wa.x + a.y * wa.y + a.z * wa.z + a.w * wa.w;
    const float4 b2 = *reinterpret_cast<const float4*>(hb + k);
    const float4 wb = *reinterpret_cast<const float4*>(&Wl[j][256 + k]);
    acc += b2.x * wb.x + b2.y * wb.y + b2.z * wb.z + b2.w * wb.w;
  }
  FE[(size_t)row * TT + j] = acc;
}

// ---------------------------------------------------------------------------
// Kernel 5: Viterbi (unchanged from R0 — correct, ~200 µs)
// ---------------------------------------------------------------------------
template <int CTRL>
__device__ __forceinline__ int dpp_i(int v) {
  return __builtin_amdgcn_mov_dpp(v, CTRL, 0xF, 0xF, true);
}
template <int CTRL>
__device__ __forceinline__ float dpp_f(float v) {
  return __int_as_float(__builtin_amdgcn_mov_dpp(__float_as_int(v), CTRL, 0xF, 0xF, true));
}
__device__ __forceinline__ float bperm_f(int lane, float v) {
  return __int_as_float(__builtin_amdgcn_ds_bpermute(lane << 2, __float_as_int(v)));
}

__global__ __launch_bounds__(1024) void viterbi(
    const float* __restrict__ FE, const float* __restrict__ trans,
    float* __restrict__ out) {
  __shared__ unsigned char bp8[LL * TT];
  __shared__ unsigned char xc[64 * 16];
  __shared__ unsigned char entry[64];
  __shared__ int sbest;
  const int t = threadIdx.x;

  if (t < 64) {
    const int n = t >> 2, pg = t & 3;
    const float tr0 = trans[n * 16 + (pg << 2) + 0];
    const float tr1 = trans[n * 16 + (pg << 2) + 1];
    const float tr2 = trans[n * 16 + (pg << 2) + 2];
    const float tr3 = trans[n * 16 + (pg << 2) + 3];
    float fvp0 = ((pg << 2) + 0 == 14) ? 0.f : NEGV;
    float fvp1 = ((pg << 2) + 1 == 14) ? 0.f : NEGV;
    float fvp2 = ((pg << 2) + 2 == 14) ? 0.f : NEGV;
    float fvp3 = ((pg << 2) + 3 == 14) ? 0.f : NEGV;

    auto step = [&](int s, float feat) {
      float bv = fvp0 + tr0; int bi = (pg << 2);
      float c;
      c = fvp1 + tr1; if (c > bv) { bv = c; bi = (pg << 2) + 1; }
      c = fvp2 + tr2; if (c > bv) { bv = c; bi = (pg << 2) + 2; }
      c = fvp3 + tr3; if (c > bv) { bv = c; bi = (pg << 2) + 3; }
      float pv = dpp_f<0xB1>(bv); int pi = dpp_i<0xB1>(bi);
      if (pv > bv || (pv == bv && pi < bi)) { bv = pv; bi = pi; }
      pv = dpp_f<0x4E>(bv); pi = dpp_i<0x4E>(bi);
      if (pv > bv || (pv == bv && pi < bi)) { bv = pv; bi = pi; }
      if (pg == 0) bp8[(s << 4) + n] = (unsigned char)bi;
      const float fvn = bv + feat;
      fvp0 = bperm_f((pg << 4) + 0,  fvn);
      fvp1 = bperm_f((pg << 4) + 4,  fvn);
      fvp2 = bperm_f((pg << 4) + 8,  fvn);
      fvp3 = bperm_f((pg << 4) + 12, fvn);
    };

    float fb0 = FE[(0 << 4) + n], fb1 = FE[(1 << 4) + n];
    float fb2 = FE[(2 << 4) + n], fb3 = FE[(3 << 4) + n];
    for (int s = 0; s < LL; s += 4) {
      step(s + 0, fb0); fb0 = (s + 4 < LL) ? FE[((s + 4) << 4) + n] : 0.f;
      step(s + 1, fb1); fb1 = (s + 5 < LL) ? FE[((s + 5) << 4) + n] : 0.f;
      step(s + 2, fb2); fb2 = (s + 6 < LL) ? FE[((s + 6) << 4) + n] : 0.f;
      step(s + 3, fb3); fb3 = (s + 7 < LL) ? FE[((s + 7) << 4) + n] : 0.f;
    }

    const float tt0 = trans[240 + (pg << 2) + 0];
    const float tt1 = trans[240 + (pg << 2) + 1];
    const float tt2 = trans[240 + (pg << 2) + 2];
    const float tt3 = trans[240 + (pg << 2) + 3];
    float bv = fvp0 + tt0; int bi = (pg << 2);
    float c;
    c = fvp1 + tt1; if (c > bv) { bv = c; bi = (pg << 2) + 1; }
    c = fvp2 + tt2; if (c > bv) { bv = c; bi = (pg << 2) + 2; }
    c = fvp3 + tt3; if (c > bv) { bv = c; bi = (pg << 2) + 3; }
    float pv = dpp_f<0xB1>(bv); int pi = dpp_i<0xB1>(bi);
    if (pv > bv || (pv == bv && pi < bi)) { bv = pv; bi = pi; }
    pv = dpp_f<0x4E>(bv); pi = dpp_i<0x4E>(bi);
    if (pv > bv || (pv == bv && pi < bi)) { bv = pv; bi = pi; }
    if (t == 0) { out[0] = bv; sbest = bi; }
  }
  __syncthreads();

  {
    const int c = t >> 4, e = t & 15;
    int tag = e;
#pragma unroll 1
    for (int i = 63; i >= 0; --i) tag = bp8[(((c << 6) + i) << 4) + tag];
    xc[(c << 4) + e] = (unsigned char)tag;
  }
  __syncthreads();
  if (t == 0) {
    int carry = sbest;
#pragma unroll 1
    for (int c = 63; c >= 0; --c) {
      entry[c] = (unsigned char)carry;
      carry = xc[(c << 4) + carry];
    }
  }
  __syncthreads();
  if (t < 64) {
    const int c = t;
    int tag = entry[c];
#pragma unroll 1
    for (int i = 63; i >= 0; --i) {
      const int s = (c << 6) + i;
      out[1 + s] = (float)tag;
      tag = bp8[(s << 4) + tag];
    }
  }
}

// ---------------------------------------------------------------------------
extern "C" void kernel_launch(void* const* d_in, const int* in_sizes, int n_in,
                              void* d_out, int out_size, void* d_ws, size_t ws_size,
                              hipStream_t stream) {
  const int*   sent = (const int*)d_in[0];
  const float* emb  = (const float*)d_in[1];
  const float* wihf = (const float*)d_in[2];
  const float* whhf = (const float*)d_in[3];
  const float* bf   = (const float*)d_in[4];
  const float* wihb = (const float*)d_in[5];
  const float* whhb = (const float*)d_in[6];
  const float* bb   = (const float*)d_in[7];
  const float* wout = (const float*)d_in[8];
  const float* bout = (const float*)d_in[9];
  const float* trans= (const float*)d_in[10];
  const float* h0   = (const float*)d_in[11];
  const float* c0   = (const float*)d_in[12];
  float* out = (float*)d_out;
  char* ws = (char*)d_ws;

  unsigned long long* SLOT = (unsigned long long*)(ws + OFF_SLOT);
  float* X    = (float*)(ws + OFF_X);
  float* ZX   = (float*)(ws + OFF_ZX);
  float* HALL = (float*)(ws + OFF_HALL);
  float* FE   = (float*)(ws + OFF_FE);

  // No memset needed: 0xAA poison never matches a valid step tag (0..4096).
  gather_x<<<(LL * (EE / 4) + 255) / 256, 256, 0, stream>>>(sent, emb, X);
  input_gemm<<<dim3(16, 64, 2), 256, 0, stream>>>(X, wihf, bf, wihb, bb, ZX);
  recurrence<<<8, 512, 0, stream>>>(whhf, whhb, h0, c0, ZX, HALL, SLOT);
  feats_gemm<<<LL / 16, 256, 0, stream>>>(HALL, wout, bout, FE);
  viterbi<<<1, 1024, 0, stream>>>(FE, trans, out);
}